// Round 8
// baseline (41.436 us; speedup 1.0000x reference)
//
#include <hip/hip_runtime.h>

// AdaptiveHyperNN, collapsed + matmul-flattened to dependency depth 2:
//   logit[b,u,v] = feat_u·va + feat_v·vb + Cb, sigmoid at the end.
//   Node 1 (independent): PM GEMM in bf16 (PM[0:256]=W1top@W2bot;
//     PM[256:512]=W2top+W1bot@W2bot; PM[512]=W2bot^T@b1+b2),
//     wa/wb = W3@w4t (fp32), c0 scalars.
//   Node 2 (8 blocks/graph): each block redundantly applies PM to wa/wb
//     (va/vb/qs/sAll — every block needs the FULL 768-vector set), gathers
//     feat to regs, A/B/sc dots, Cb, sigmoid slice.
// Lessons: R3 cross-block atomics 15-20 µs/round — never. R4: <16 CUs
// streaming = latency-bound. R5: deep serial k-loops — split k over waves.
// R6: per-block GEMM B-read is fixed — fewer, fatter blocks. R7: graph-node
// slot ≈ 5-6 µs dominates tiny execs — cut node count; bf16 the redundant
// PM read to halve its per-CU cost.

__device__ __forceinline__ float wred(float v) {
#pragma unroll
  for (int o = 32; o > 0; o >>= 1) v += __shfl_xor(v, o, 64);
  return v;
}
__device__ __forceinline__ float dot4(float4 a, float4 b) {
  return a.x * b.x + a.y * b.y + a.z * b.z + a.w * b.w;
}
__device__ __forceinline__ unsigned short f2bf(float x) {  // RNE, finite data
  union { float f; unsigned int u; } v; v.f = x;
  unsigned int r = (v.u + 0x7fffu + ((v.u >> 16) & 1u)) >> 16;
  return (unsigned short)r;
}
__device__ __forceinline__ float bf2f(unsigned short h) {
  union { unsigned int u; float f; } v; v.u = ((unsigned int)h) << 16;
  return v.f;
}

// ws layout: PMh = 513*256 ushorts (= 65664 floats) at base; then fp32.
#define PMH_ROWS 513
#define OFF_WA   65664
#define OFF_WB   (OFF_WA + 256)
#define OFF_C0   (OFF_WB + 256)   // 8 floats

// Node 1. blocks 0..63: PM GEMM, 8 rows/block, k split over 4 waves;
// blocks 64..191: wa/wb wave-per-row; block 192: c0 + PM[512].
__global__ __launch_bounds__(256) void k1(
    const float* __restrict__ Xs,
    const float* __restrict__ W1, const float* __restrict__ b1,
    const float* __restrict__ W2, const float* __restrict__ b2,
    const float* __restrict__ W3, const float* __restrict__ b3,
    const float* __restrict__ W4, const float* __restrict__ b4,
    float* __restrict__ ws) {
  const int blk = blockIdx.x, tid = threadIdx.x;
  unsigned short* PMh = (unsigned short*)ws;
  const float* W2bot = W2 + 256 * 256;
  __shared__ float w1s[8][256];
  __shared__ float4 part[8][4][64];

  if (blk < 64) {
    // ---- PM rows r0..r0+7 ----
    const int r0 = blk * 8;
    const int c4 = tid & 63, wv = tid >> 6;
#pragma unroll
    for (int i = 0; i < 8; ++i)
      ((float*)w1s)[i * 256 + tid] = W1[(size_t)r0 * 256 + i * 256 + tid];
    __syncthreads();
    const float4* w2b4 = (const float4*)W2bot;
    float4 acc[8];
#pragma unroll
    for (int i = 0; i < 8; ++i) acc[i] = make_float4(0.f, 0.f, 0.f, 0.f);
    const int kb = wv * 64;
#pragma unroll 4
    for (int i = 0; i < 64; ++i) {
      int k = kb + i;
      float4 w = w2b4[k * 64 + c4];
#pragma unroll
      for (int r = 0; r < 8; ++r) {
        float x = w1s[r][k];
        acc[r].x += x * w.x; acc[r].y += x * w.y;
        acc[r].z += x * w.z; acc[r].w += x * w.w;
      }
    }
#pragma unroll
    for (int r = 0; r < 8; ++r) part[r][wv][c4] = acc[r];
    __syncthreads();
    // 512 outputs (row,c4) over 256 threads, 2 each; fixed order 0+1+2+3
#pragma unroll
    for (int j = 0; j < 2; ++j) {
      int item = tid + j * 256;
      int row = item >> 6, c = item & 63;
      float4 p0 = part[row][0][c], p1 = part[row][1][c];
      float4 p2 = part[row][2][c], p3 = part[row][3][c];
      float4 s = make_float4(p0.x + p1.x + p2.x + p3.x,
                             p0.y + p1.y + p2.y + p3.y,
                             p0.z + p1.z + p2.z + p3.z,
                             p0.w + p1.w + p2.w + p3.w);
      int r = r0 + row;
      if (r >= 256) {
        float4 t = ((const float4*)(W2 + (size_t)(r - 256) * 256))[c];
        s.x += t.x; s.y += t.y; s.z += t.z; s.w += t.w;
      }
      ushort4 h;
      h.x = f2bf(s.x); h.y = f2bf(s.y); h.z = f2bf(s.z); h.w = f2bf(s.w);
      ((ushort4*)(PMh + (size_t)r * 256))[c] = h;
    }
  } else if (blk < 192) {
    // ---- wa/wb = W3 @ w4t, wave per row (fp32) ----
    const int lane = tid & 63, wv = tid >> 6;
    const int t = (blk - 64) * 4 + wv;  // 0..511
    float4 w4a = ((const float4*)W4)[lane];
    float4 rv = ((const float4*)(W3 + (size_t)t * 256))[lane];
    float s = wred(dot4(rv, w4a));
    if (lane == 0) {
      if (t < 256) ws[OFF_WA + t] = s; else ws[OFF_WB + t - 256] = s;
    }
  } else {
    // ---- c0 scalars + PM[512] = W2bot^T @ b1 + b2 (bf16) ----
    const int lane = tid & 63, wv = tid >> 6;
    float4 w4a = ((const float4*)W4)[lane];
    float4 w4b4 = ((const float4*)W4)[lane + 64];
    float sb3 = wred(dot4(((const float4*)b3)[lane], w4a));
    for (int bi = wv; bi < 8; bi += 4) {
      float xd = wred(dot4(((const float4*)(Xs + (size_t)bi * 256))[lane], w4b4));
      if (lane == 0) ws[OFF_C0 + bi] = b4[0] + sb3 + xd;
    }
    const int c4 = tid & 63, rg = tid >> 6;
    const float4* w2b4 = (const float4*)W2bot;
    float4 acc = make_float4(0.f, 0.f, 0.f, 0.f);
#pragma unroll 8
    for (int i = 0; i < 64; ++i) {
      int k = rg * 64 + i;
      float4 w = w2b4[k * 64 + c4];
      float bv = b1[k];
      acc.x += bv * w.x; acc.y += bv * w.y; acc.z += bv * w.z; acc.w += bv * w.w;
    }
    part[0][rg][c4] = acc;
    __syncthreads();
    if (tid < 64) {
      float4 p0 = part[0][0][tid], p1 = part[0][1][tid];
      float4 p2 = part[0][2][tid], p3 = part[0][3][tid];
      float4 bb = ((const float4*)b2)[tid];
      float4 s = make_float4(p0.x + p1.x + p2.x + p3.x + bb.x,
                             p0.y + p1.y + p2.y + p3.y + bb.y,
                             p0.z + p1.z + p2.z + p3.z + bb.z,
                             p0.w + p1.w + p2.w + p3.w + bb.w);
      ushort4 h;
      h.x = f2bf(s.x); h.y = f2bf(s.y); h.z = f2bf(s.z); h.w = f2bf(s.w);
      ((ushort4*)(PMh + (size_t)512 * 256))[tid] = h;
    }
  }
}

// Node 2: 8 blocks per graph (64 total), 1024 threads. Each block:
// (1) issues its graph's feat gathers (L3-resident api) so they fly under
// (2) the redundant PM matvec: rows 0..255 -> qs, 256..511 -> va/vb,
//     512 -> sAll (identical op order in every block -> identical values),
// (3) A/B/sc dots, Cb, 16-row sigmoid slice.
__global__ __launch_bounds__(1024) void k23(
    const float* __restrict__ api, const int* __restrict__ invoked,
    const float* __restrict__ ws, float* __restrict__ out) {
  const int g = blockIdx.x >> 3, sub = blockIdx.x & 7;
  const int tid = threadIdx.x;
  const int lane = tid & 63, wv = tid >> 6;  // wv 0..15
  const unsigned short* PMh = (const unsigned short*)ws;
  __shared__ alignas(16) float qsL[256], vaL[256], vbL[256];
  __shared__ alignas(16) float Ash[128], Bsh[128], scsh[128];
  __shared__ float CbSh, sAllSh;

  // (1) gather 8 rows/wave into regs
  float4 f[8];
  const int ub = wv * 8;
  int idx[8];
#pragma unroll
  for (int i = 0; i < 8; ++i) idx[i] = invoked[(g << 7) + ub + i];
#pragma unroll
  for (int i = 0; i < 8; ++i)
    f[i] = ((const float4*)(api + (size_t)idx[i] * 256))[lane];

  // (2) PM matvec, wave-per-row, rows t = wv, wv+16, ... , <=512
  float4 wa4 = ((const float4*)(ws + OFF_WA))[lane];
  float4 wb4 = ((const float4*)(ws + OFF_WB))[lane];
  float4 sm4 = make_float4(wa4.x + wb4.x, wa4.y + wb4.y,
                           wa4.z + wb4.z, wa4.w + wb4.w);
#pragma unroll 4
  for (int t = wv; t < 513; t += 16) {
    ushort4 h = ((const ushort4*)(PMh + (size_t)t * 256))[lane];
    float4 m = make_float4(bf2f(h.x), bf2f(h.y), bf2f(h.z), bf2f(h.w));
    if (t < 256) {
      float s = wred(dot4(m, sm4));
      if (lane == 0) qsL[t] = s;
    } else if (t < 512) {
      float sa = dot4(m, wa4);
      float sb = dot4(m, wb4);
      sa = wred(sa); sb = wred(sb);
      if (lane == 0) { vaL[t - 256] = sa; vbL[t - 256] = sb; }
    } else {
      float s = wred(dot4(m, sm4));
      if (lane == 0) sAllSh = s;
    }
  }
  __syncthreads();

  // (3) A/B/sc dots (all rows; identical order per block)
  float4 va4 = ((const float4*)vaL)[lane];
  float4 vb4 = ((const float4*)vbL)[lane];
  float4 q4  = ((const float4*)qsL)[lane];
#pragma unroll
  for (int i = 0; i < 8; ++i) {
    float sa = wred(dot4(f[i], va4));
    float sb = wred(dot4(f[i], vb4));
    float sc = wred(dot4(f[i], q4));
    if (lane == 0) { Ash[ub + i] = sa; Bsh[ub + i] = sb; scsh[ub + i] = sc; }
  }
  __syncthreads();
  if (wv == 0) {  // deterministic fixed-order Cb reduction
    float t = scsh[lane] + scsh[lane + 64];
    t = wred(t);
    if (lane == 0) CbSh = t * (1.f / 128.f) + ws[OFF_C0 + g] + sAllSh;
  }
  __syncthreads();
  const float Cb = CbSh;
  // this block's slice: u in [sub*16, sub*16+16) -> 16*32 = 512 float4
  if (tid < 512) {
    int u = (sub << 4) + (tid >> 5);   // 32 float4 per row
    int v4 = tid & 31;
    float a = Ash[u] + Cb;
    float4 bv = ((const float4*)Bsh)[v4];
    float4 r;
    r.x = 1.f / (1.f + __expf(-(a + bv.x)));
    r.y = 1.f / (1.f + __expf(-(a + bv.y)));
    r.z = 1.f / (1.f + __expf(-(a + bv.z)));
    r.w = 1.f / (1.f + __expf(-(a + bv.w)));
    ((float4*)(out + (g << 14) + (u << 7)))[v4] = r;
  }
}

extern "C" void kernel_launch(void* const* d_in, const int* in_sizes, int n_in,
                              void* d_out, int out_size, void* d_ws, size_t ws_size,
                              hipStream_t stream) {
  const float* Xs  = (const float*)d_in[0];
  const float* api = (const float*)d_in[1];
  const float* W1  = (const float*)d_in[2];
  const float* b1  = (const float*)d_in[3];
  const float* W2  = (const float*)d_in[4];
  const float* b2  = (const float*)d_in[5];
  const float* W3  = (const float*)d_in[6];
  const float* b3  = (const float*)d_in[7];
  const float* W4  = (const float*)d_in[8];
  const float* b4  = (const float*)d_in[9];
  const int* invoked = (const int*)d_in[10];
  float* out = (float*)d_out;
  float* ws = (float*)d_ws;

  hipLaunchKernelGGL(k1, dim3(193), dim3(256), 0, stream,
                     Xs, W1, b1, W2, b2, W3, b3, W4, b4, ws);
  hipLaunchKernelGGL(k23, dim3(64), dim3(1024), 0, stream,
                     api, invoked, ws, out);
}

// Round 9
// 26.075 us; speedup vs baseline: 1.5891x; 1.5891x over previous
//
#include <hip/hip_runtime.h>

// AdaptiveHyperNN, collapsed + matmul-flattened to dependency depth 2:
//   logit[b,u,v] = feat_u·va + feat_v·vb + Cb, sigmoid at the end.
//   Node 1: PMt = transpose(PM) in bf16, where PM[0:256]=W1top@W2bot (qs),
//     PM[256:512]=W2top+W1bot@W2bot (va/vb); rowS=W2bot^T@b1+b2 (fp32);
//     wa/wb = W3@w4t (fp32); c0 scalars.
//   Node 2 (8 blocks/graph): redundant matvec via PMt with
//     THREAD-PER-OUTPUT register accumulation (no shuffles), then gather
//     feat -> regs (short live range), A/B/sc dots, Cb, sigmoid slice.
// Lessons: R3 cross-block atomics 15-20 µs/round. R4: <16 CUs streaming =
// latency-bound. R5: split deep k-loops over waves. R6: fewer fatter GEMM
// blocks. R7: node slot ≈ 5-6 µs — cut node count. R8: redundant work must
// be throughput-shaped (per-thread acc), never wave-wred chains; don't
// hold gather regs across a long phase (spills).

__device__ __forceinline__ float wred(float v) {
#pragma unroll
  for (int o = 32; o > 0; o >>= 1) v += __shfl_xor(v, o, 64);
  return v;
}
__device__ __forceinline__ float dot4(float4 a, float4 b) {
  return a.x * b.x + a.y * b.y + a.z * b.z + a.w * b.w;
}
__device__ __forceinline__ unsigned short f2bf(float x) {  // RNE, finite data
  union { float f; unsigned int u; } v; v.f = x;
  unsigned int r = (v.u + 0x7fffu + ((v.u >> 16) & 1u)) >> 16;
  return (unsigned short)r;
}
__device__ __forceinline__ float bf2f(unsigned short h) {
  union { unsigned int u; float f; } v; v.u = ((unsigned int)h) << 16;
  return v.f;
}

// ws layout (float units). PMt = 256x512 bf16 (k-major): 65536 floats.
#define OFF_WA   65536
#define OFF_WB   65792
#define OFF_ROWS 66048   // rowS, 256 fp32
#define OFF_C0   66304   // 8 fp32

// Node 1. blocks 0..63: PM GEMM (8 rows/block, k split over 4 waves),
// LDS-transposed bf16 store into PMt; blocks 64..191: wa/wb wave-per-row;
// block 192: c0 + rowS.
__global__ __launch_bounds__(256) void k1(
    const float* __restrict__ Xs,
    const float* __restrict__ W1, const float* __restrict__ b1,
    const float* __restrict__ W2, const float* __restrict__ b2,
    const float* __restrict__ W3, const float* __restrict__ b3,
    const float* __restrict__ W4, const float* __restrict__ b4,
    float* __restrict__ ws) {
  const int blk = blockIdx.x, tid = threadIdx.x;
  unsigned short* PMt = (unsigned short*)ws;
  const float* W2bot = W2 + 256 * 256;
  __shared__ float w1s[8][256];          // reused as transpose tile
  __shared__ float4 part[8][4][64];

  if (blk < 64) {
    // ---- PM rows r0..r0+7 ----
    const int r0 = blk * 8;
    const int c4 = tid & 63, wv = tid >> 6;
#pragma unroll
    for (int i = 0; i < 8; ++i)
      ((float*)w1s)[i * 256 + tid] = W1[(size_t)r0 * 256 + i * 256 + tid];
    __syncthreads();
    const float4* w2b4 = (const float4*)W2bot;
    float4 acc[8];
#pragma unroll
    for (int i = 0; i < 8; ++i) acc[i] = make_float4(0.f, 0.f, 0.f, 0.f);
    const int kb = wv * 64;
#pragma unroll 4
    for (int i = 0; i < 64; ++i) {
      int k = kb + i;
      float4 w = w2b4[k * 64 + c4];
#pragma unroll
      for (int r = 0; r < 8; ++r) {
        float x = w1s[r][k];
        acc[r].x += x * w.x; acc[r].y += x * w.y;
        acc[r].z += x * w.z; acc[r].w += x * w.w;
      }
    }
#pragma unroll
    for (int r = 0; r < 8; ++r) part[r][wv][c4] = acc[r];
    __syncthreads();   // also: w1s dead, safe to reuse as tile
    // combine partials (fixed order 0+1+2+3) into tile[row][c]
#pragma unroll
    for (int j = 0; j < 2; ++j) {
      int item = tid + j * 256;
      int row = item >> 6, c = item & 63;
      float4 p0 = part[row][0][c], p1 = part[row][1][c];
      float4 p2 = part[row][2][c], p3 = part[row][3][c];
      float4 s = make_float4(p0.x + p1.x + p2.x + p3.x,
                             p0.y + p1.y + p2.y + p3.y,
                             p0.z + p1.z + p2.z + p3.z,
                             p0.w + p1.w + p2.w + p3.w);
      int r = r0 + row;
      if (r >= 256) {
        float4 t = ((const float4*)(W2 + (size_t)(r - 256) * 256))[c];
        s.x += t.x; s.y += t.y; s.z += t.z; s.w += t.w;
      }
      ((float4*)w1s[row])[c] = s;
    }
    __syncthreads();
    // transposed bf16 store: thread c writes PMt[c][r0..r0+7] (16 B)
    if (tid < 256) {
      unsigned int p0 = (unsigned int)f2bf(w1s[0][tid]) |
                        ((unsigned int)f2bf(w1s[1][tid]) << 16);
      unsigned int p1 = (unsigned int)f2bf(w1s[2][tid]) |
                        ((unsigned int)f2bf(w1s[3][tid]) << 16);
      unsigned int p2 = (unsigned int)f2bf(w1s[4][tid]) |
                        ((unsigned int)f2bf(w1s[5][tid]) << 16);
      unsigned int p3 = (unsigned int)f2bf(w1s[6][tid]) |
                        ((unsigned int)f2bf(w1s[7][tid]) << 16);
      uint4 v = make_uint4(p0, p1, p2, p3);
      *((uint4*)(PMt + (size_t)tid * 512 + r0)) = v;
    }
  } else if (blk < 192) {
    // ---- wa/wb = W3 @ w4t, wave per row (fp32) ----
    const int lane = tid & 63, wv = tid >> 6;
    const int t = (blk - 64) * 4 + wv;  // 0..511
    float4 w4a = ((const float4*)W4)[lane];
    float4 rv = ((const float4*)(W3 + (size_t)t * 256))[lane];
    float s = wred(dot4(rv, w4a));
    if (lane == 0) {
      if (t < 256) ws[OFF_WA + t] = s; else ws[OFF_WB + t - 256] = s;
    }
  } else {
    // ---- c0 scalars + rowS = W2bot^T @ b1 + b2 (fp32) ----
    const int lane = tid & 63, wv = tid >> 6;
    float4 w4a = ((const float4*)W4)[lane];
    float4 w4b4 = ((const float4*)W4)[lane + 64];
    float sb3 = wred(dot4(((const float4*)b3)[lane], w4a));
    for (int bi = wv; bi < 8; bi += 4) {
      float xd = wred(dot4(((const float4*)(Xs + (size_t)bi * 256))[lane], w4b4));
      if (lane == 0) ws[OFF_C0 + bi] = b4[0] + sb3 + xd;
    }
    const int c4 = tid & 63, rg = tid >> 6;
    const float4* w2b4 = (const float4*)W2bot;
    float4 acc = make_float4(0.f, 0.f, 0.f, 0.f);
#pragma unroll 8
    for (int i = 0; i < 64; ++i) {
      int k = rg * 64 + i;
      float4 w = w2b4[k * 64 + c4];
      float bv = b1[k];
      acc.x += bv * w.x; acc.y += bv * w.y; acc.z += bv * w.z; acc.w += bv * w.w;
    }
    part[0][rg][c4] = acc;
    __syncthreads();
    if (tid < 64) {
      float4 p0 = part[0][0][tid], p1 = part[0][1][tid];
      float4 p2 = part[0][2][tid], p3 = part[0][3][tid];
      float4 bb = ((const float4*)b2)[tid];
      float4 s = make_float4(p0.x + p1.x + p2.x + p3.x + bb.x,
                             p0.y + p1.y + p2.y + p3.y + bb.y,
                             p0.z + p1.z + p2.z + p3.z + bb.z,
                             p0.w + p1.w + p2.w + p3.w + bb.w);
      ((float4*)(ws + OFF_ROWS))[tid] = s;
    }
  }
}

// Node 2: 8 blocks per graph (64 total), 1024 threads.
// Phase A: redundant matvec via PMt, thread-per-output (r = tid&511,
//   k-half = tid>>9), zero shuffles; combine halves through LDS (fixed
//   order) -> qsL/vaL/vbL; wave 15 does the single sAll wred.
// Phase B: gather feat rows (short-lived regs), A/B/sc wred dots.
// Phase C: Cb, 16-row sigmoid slice.
__global__ __launch_bounds__(1024) void k23(
    const float* __restrict__ api, const int* __restrict__ invoked,
    const float* __restrict__ ws, float* __restrict__ out) {
  const int g = blockIdx.x >> 3, sub = blockIdx.x & 7;
  const int tid = threadIdx.x;
  const int lane = tid & 63, wv = tid >> 6;  // wv 0..15
  const unsigned short* PMt = (const unsigned short*)ws;
  __shared__ float waL[256], wbL[256];
  __shared__ float pQ[2][256], pA[2][256], pB[2][256];
  __shared__ alignas(16) float qsL[256], vaL[256], vbL[256];
  __shared__ alignas(16) float Ash[128], Bsh[128], scsh[128];
  __shared__ float CbSh, sAllSh;

  if (tid < 256) { waL[tid] = ws[OFF_WA + tid]; wbL[tid] = ws[OFF_WB + tid]; }
  __syncthreads();

  // ---- phase A: thread-per-output matvec, k in wave-uniform halves ----
  {
    const int r = tid & 511, kh = tid >> 9;   // kh uniform per wave
    const int k0 = kh << 7;
    const unsigned short* col = PMt + r;      // element (k,r) at col[k*512]
    if (r < 256) {
      float a0 = 0.f, a1 = 0.f;
#pragma unroll 8
      for (int i = 0; i < 128; i += 2) {
        int k = k0 + i;
        float m0 = bf2f(col[(size_t)k * 512]);
        float m1 = bf2f(col[(size_t)(k + 1) * 512]);
        a0 += m0 * (waL[k] + wbL[k]);
        a1 += m1 * (waL[k + 1] + wbL[k + 1]);
      }
      pQ[kh][r] = a0 + a1;
    } else {
      float aa0 = 0.f, aa1 = 0.f, bb0 = 0.f, bb1 = 0.f;
#pragma unroll 8
      for (int i = 0; i < 128; i += 2) {
        int k = k0 + i;
        float m0 = bf2f(col[(size_t)k * 512]);
        float m1 = bf2f(col[(size_t)(k + 1) * 512]);
        aa0 += m0 * waL[k];     bb0 += m0 * wbL[k];
        aa1 += m1 * waL[k + 1]; bb1 += m1 * wbL[k + 1];
      }
      pA[kh][r - 256] = aa0 + aa1;
      pB[kh][r - 256] = bb0 + bb1;
    }
  }
  __syncthreads();
  if (tid < 256) {
    qsL[tid] = pQ[0][tid] + pQ[1][tid];
  } else if (tid < 512) {
    int i = tid - 256; vaL[i] = pA[0][i] + pA[1][i];
  } else if (tid < 768) {
    int i = tid - 512; vbL[i] = pB[0][i] + pB[1][i];
  } else if (wv == 15) {  // sAll = rowS·(wa+wb): the one wred of phase A
    float4 rs = ((const float4*)(ws + OFF_ROWS))[lane];
    int k = lane * 4;
    float s = rs.x * (waL[k] + wbL[k]) + rs.y * (waL[k + 1] + wbL[k + 1]) +
              rs.z * (waL[k + 2] + wbL[k + 2]) + rs.w * (waL[k + 3] + wbL[k + 3]);
    s = wred(s);
    if (lane == 0) sAllSh = s;
  }
  __syncthreads();

  // ---- phase B: gather + A/B/sc dots (identical order in all blocks) ----
  {
    float4 f[8];
    const int ub = wv * 8;
    int idx[8];
#pragma unroll
    for (int i = 0; i < 8; ++i) idx[i] = invoked[(g << 7) + ub + i];
#pragma unroll
    for (int i = 0; i < 8; ++i)
      f[i] = ((const float4*)(api + (size_t)idx[i] * 256))[lane];
    float4 va4 = ((const float4*)vaL)[lane];
    float4 vb4 = ((const float4*)vbL)[lane];
    float4 q4  = ((const float4*)qsL)[lane];
#pragma unroll
    for (int i = 0; i < 8; ++i) {
      float sa = wred(dot4(f[i], va4));
      float sb = wred(dot4(f[i], vb4));
      float sc = wred(dot4(f[i], q4));
      if (lane == 0) { Ash[ub + i] = sa; Bsh[ub + i] = sb; scsh[ub + i] = sc; }
    }
  }
  __syncthreads();
  if (wv == 0) {  // deterministic fixed-order Cb reduction
    float t = scsh[lane] + scsh[lane + 64];
    t = wred(t);
    if (lane == 0) CbSh = t * (1.f / 128.f) + ws[OFF_C0 + g] + sAllSh;
  }
  __syncthreads();

  // ---- phase C: 16-row sigmoid slice ----
  const float Cb = CbSh;
  if (tid < 512) {
    int u = (sub << 4) + (tid >> 5);   // 32 float4 per row
    int v4 = tid & 31;
    float a = Ash[u] + Cb;
    float4 bv = ((const float4*)Bsh)[v4];
    float4 r;
    r.x = 1.f / (1.f + __expf(-(a + bv.x)));
    r.y = 1.f / (1.f + __expf(-(a + bv.y)));
    r.z = 1.f / (1.f + __expf(-(a + bv.z)));
    r.w = 1.f / (1.f + __expf(-(a + bv.w)));
    ((float4*)(out + (g << 14) + (u << 7)))[v4] = r;
  }
}

extern "C" void kernel_launch(void* const* d_in, const int* in_sizes, int n_in,
                              void* d_out, int out_size, void* d_ws, size_t ws_size,
                              hipStream_t stream) {
  const float* Xs  = (const float*)d_in[0];
  const float* api = (const float*)d_in[1];
  const float* W1  = (const float*)d_in[2];
  const float* b1  = (const float*)d_in[3];
  const float* W2  = (const float*)d_in[4];
  const float* b2  = (const float*)d_in[5];
  const float* W3  = (const float*)d_in[6];
  const float* b3  = (const float*)d_in[7];
  const float* W4  = (const float*)d_in[8];
  const float* b4  = (const float*)d_in[9];
  const int* invoked = (const int*)d_in[10];
  float* out = (float*)d_out;
  float* ws = (float*)d_ws;

  hipLaunchKernelGGL(k1, dim3(193), dim3(256), 0, stream,
                     Xs, W1, b1, W2, b2, W3, b3, W4, b4, ws);
  hipLaunchKernelGGL(k23, dim3(64), dim3(1024), 0, stream,
                     api, invoked, ws, out);
}